// Round 15
// baseline (424.632 us; speedup 1.0000x reference)
//
#include <hip/hip_runtime.h>
#include <hip/hip_bf16.h>

typedef __attribute__((ext_vector_type(8))) short short8;
typedef __attribute__((ext_vector_type(8))) unsigned short ushort8;
typedef __attribute__((ext_vector_type(4))) float f32x4;
typedef unsigned short u16;
typedef unsigned long long u64;

#define IN_C 128
#define OUT_C 256
#define LN_EPS 1e-5f
#define CHUNK 512
#define WSCALE 1048576.0f   // 2^20 fixed-point for packed degree

__device__ __forceinline__ u16 f2bf(float f) {
    __hip_bfloat16 h = __float2bfloat16(f);
    return __builtin_bit_cast(u16, h);
}

// zero pk[N] (8N bytes) with vector stores
__global__ void k_zero(float4* __restrict__ p, int n4) {
    int i = blockIdx.x * 256 + threadIdx.x;
    if (i < n4) p[i] = make_float4(0.f, 0.f, 0.f, 0.f);
}

// Fused: packed {count, weighted-degree} histogram (blocks [0,nbc)) and
// W-fragment pack + combined bias (blocks [nbc, nbc+32)).
__global__ void k_count(const int* __restrict__ ei, const float* __restrict__ ew,
                        u64* __restrict__ pk, int E, int nbc,
                        const float* __restrict__ Wg, const float* __restrict__ Wr,
                        const float* __restrict__ bg, const float* __restrict__ br,
                        u16* __restrict__ wfrag, float* __restrict__ bc) {
    int b = blockIdx.x;
    if (b < nbc) {
        int e = b * 256 + threadIdx.x;
        if (e < E) {
            int c = ei[E + e];
            unsigned w = (unsigned)(ew[e & 31] * WSCALE + 0.5f);
            atomicAdd(&pk[c], (1ULL << 32) | (u64)w);
        }
        return;
    }
    // ---- wprep part ----
    int tid = (b - nbc) * 256 + threadIdx.x;
    if (tid < OUT_C) bc[tid] = bg[tid] + br[tid];
    if (tid >= 8192) return;
    int l = tid & 63;
    int t = (tid >> 6) & 15;
    int s = tid >> 10;
    int n = t * 16 + (l & 15);
    int k0 = s * 32 + (l >> 4) * 8;
    short8 pkk;
#pragma unroll
    for (int j = 0; j < 8; ++j) {
        int k = k0 + j;
        float w = (k < IN_C) ? Wg[k * OUT_C + n] : Wr[(k - IN_C) * OUT_C + n];
        pkk[j] = (short)f2bf(w);
    }
    reinterpret_cast<short8*>(wfrag)[tid] = pkk;
}

// ---- exclusive scan of cnt -> off, cur = copy; dinv computed from packed ----
__global__ void k_scan1(const u64* __restrict__ pk, int* __restrict__ partial,
                        float* __restrict__ dinv, int n) {
    __shared__ int sm[256];
    int b = blockIdx.x, t = threadIdx.x;
    int base = b * 1024 + t * 4;
    int s = 0;
#pragma unroll
    for (int k = 0; k < 4; ++k) {
        int i = base + k;
        if (i < n) {
            u64 v = pk[i];
            s += (int)(v >> 32);
            dinv[i] = rsqrtf(1.0f + (float)(unsigned)(v & 0xffffffffULL) * (1.0f / WSCALE));
        }
    }
    sm[t] = s; __syncthreads();
    for (int m = 128; m > 0; m >>= 1) { if (t < m) sm[t] += sm[t + m]; __syncthreads(); }
    if (t == 0) partial[b] = sm[0];
}

__global__ void k_scan2(int* __restrict__ partial, int nb) {
    __shared__ int sm[512];
    int t = threadIdx.x;
    sm[t] = (t < nb) ? partial[t] : 0;
    __syncthreads();
    for (int d = 1; d < 512; d <<= 1) {
        int v = (t >= d) ? sm[t - d] : 0;
        __syncthreads();
        sm[t] += v;
        __syncthreads();
    }
    if (t < nb) partial[t] = (t == 0) ? 0 : sm[t - 1];
}

__global__ void k_scan3(const u64* __restrict__ pk, const int* __restrict__ partial,
                        int* __restrict__ off, int* __restrict__ cur, int n, int E) {
    __shared__ int sm[256];
    int b = blockIdx.x, t = threadIdx.x;
    int base = b * 1024 + t * 4;
    int c[4]; int s = 0;
#pragma unroll
    for (int k = 0; k < 4; ++k) {
        int i = base + k;
        c[k] = (i < n) ? (int)(pk[i] >> 32) : 0;
        s += c[k];
    }
    sm[t] = s; __syncthreads();
    for (int d = 1; d < 256; d <<= 1) {
        int v = (t >= d) ? sm[t - d] : 0;
        __syncthreads();
        sm[t] += v;
        __syncthreads();
    }
    int run = partial[b] + (sm[t] - s);
#pragma unroll
    for (int k = 0; k < 4; ++k) {
        int i = base + k;
        if (i < n) { off[i] = run; cur[i] = run; }
        run += c[k];
    }
    if (b == 0 && t == 0) off[n] = E;
}

// place edge records {src, norm} grouped by target col
__global__ void k_place(const int* __restrict__ ei, const float* __restrict__ ew,
                        const float* __restrict__ dinv, int* __restrict__ cur,
                        int2* __restrict__ rec2, int E) {
    int e = blockIdx.x * 256 + threadIdx.x;
    if (e >= E) return;
    int r = ei[e], c = ei[E + e];
    float nrm = dinv[r] * ew[e & 31] * dinv[c];
    int p = atomicAdd(&cur[c], 1);
    rec2[p] = make_int2(r, __float_as_int(nrm));
}

// Fused: LDS-staged CSR records + batched independent gathers (register accum)
// -> bf16 LDS-A ; h = [u|x]@Wc+bc ; LN ; relu ; store.
// BM=32 rows/block, 256 threads = 4 waves (2 rows/thread staging);
// wave wv owns cols [wv*64, wv*64+64). Small blocks -> ~7 resident/CU.
__global__ __launch_bounds__(256, 8) void k_gemm(
    const float4* __restrict__ x4, const float* __restrict__ dinv,
    const int* __restrict__ off, const int2* __restrict__ rec2g,
    const u16* __restrict__ wfrag, const float* __restrict__ bc,
    const float* __restrict__ gamma, const float* __restrict__ beta,
    float* __restrict__ out, int N) {

    __shared__ u16 A[32 * 264];      // [32 rows][256 bf16 + 8 pad]: 0..127 u, 128..255 x
    __shared__ float red[4 * 32 * 2];
    __shared__ float fin[32 * 2];
    __shared__ int2 recs[CHUNK];     // staged CSR records for this block

    const int tid = threadIdx.x;
    const int lane = tid & 63;
    const int wv = tid >> 6;         // 0..3
    const long r0 = (long)blockIdx.x * 32;

    const int trow = tid >> 4;       // 0..15 -> owns rows trow and trow+16
    const int tq = tid & 15;         // owns floats [tq*8, tq*8+8)

    // ---- phase 1: self-loop init in regs + x-half of A (both rows) ----
    float uaA[8], uaB[8];
    int pA0 = 0, pA1 = 0, pB0 = 0, pB1 = 0;
    {
        const long gr = r0 + trow;
        u16* xp = &A[trow * 264 + 128 + tq * 8];
        if (gr < N) {
            float d = dinv[gr];
            float d2 = d * d;
            const float4* xs = x4 + gr * 32 + tq * 2;
            float4 v0 = xs[0], v1 = xs[1];
            ushort4 x0, x1;
            x0.x = f2bf(v0.x); x0.y = f2bf(v0.y); x0.z = f2bf(v0.z); x0.w = f2bf(v0.w);
            x1.x = f2bf(v1.x); x1.y = f2bf(v1.y); x1.z = f2bf(v1.z); x1.w = f2bf(v1.w);
            *reinterpret_cast<ushort4*>(xp) = x0;
            *reinterpret_cast<ushort4*>(xp + 4) = x1;
            uaA[0] = v0.x * d2; uaA[1] = v0.y * d2; uaA[2] = v0.z * d2; uaA[3] = v0.w * d2;
            uaA[4] = v1.x * d2; uaA[5] = v1.y * d2; uaA[6] = v1.z * d2; uaA[7] = v1.w * d2;
            pA0 = off[gr]; pA1 = off[gr + 1];
        } else {
#pragma unroll
            for (int k = 0; k < 8; ++k) uaA[k] = 0.f;
            ushort4 zz = {0, 0, 0, 0};
            *reinterpret_cast<ushort4*>(xp) = zz;
            *reinterpret_cast<ushort4*>(xp + 4) = zz;
        }
    }
    {
        const long gr = r0 + trow + 16;
        u16* xp = &A[(trow + 16) * 264 + 128 + tq * 8];
        if (gr < N) {
            float d = dinv[gr];
            float d2 = d * d;
            const float4* xs = x4 + gr * 32 + tq * 2;
            float4 v0 = xs[0], v1 = xs[1];
            ushort4 x0, x1;
            x0.x = f2bf(v0.x); x0.y = f2bf(v0.y); x0.z = f2bf(v0.z); x0.w = f2bf(v0.w);
            x1.x = f2bf(v1.x); x1.y = f2bf(v1.y); x1.z = f2bf(v1.z); x1.w = f2bf(v1.w);
            *reinterpret_cast<ushort4*>(xp) = x0;
            *reinterpret_cast<ushort4*>(xp + 4) = x1;
            uaB[0] = v0.x * d2; uaB[1] = v0.y * d2; uaB[2] = v0.z * d2; uaB[3] = v0.w * d2;
            uaB[4] = v1.x * d2; uaB[5] = v1.y * d2; uaB[6] = v1.z * d2; uaB[7] = v1.w * d2;
            pB0 = off[gr]; pB1 = off[gr + 1];
        } else {
#pragma unroll
            for (int k = 0; k < 8; ++k) uaB[k] = 0.f;
            ushort4 zz = {0, 0, 0, 0};
            *reinterpret_cast<ushort4*>(xp) = zz;
            *reinterpret_cast<ushort4*>(xp + 4) = zz;
        }
    }

    // ---- phase 2: chunked record staging + batched independent gathers ----
    const int rend = (int)((r0 + 32 < N) ? (r0 + 32) : N);
    const int e0 = off[r0];
    const int e1 = off[rend];
    for (int cb = e0; cb < e1; cb += CHUNK) {
        const int ce = (cb + CHUNK < e1) ? (cb + CHUNK) : e1;
        __syncthreads();   // recs reuse guard
        for (int i = tid; i < ce - cb; i += 256) recs[i] = rec2g[cb + i];
        __syncthreads();
        // row A
        {
            const int q0 = (pA0 > cb) ? pA0 : cb;
            const int q1 = (pA1 < ce) ? pA1 : ce;
            for (int p = q0; p < q1; p += 4) {
                const int nb = q1 - p;
                int sr[4]; float nr[4];
                float4 ga[4][2];
#pragma unroll
                for (int b = 0; b < 4; ++b) {
                    if (b < nb) {
                        int2 rc = recs[p - cb + b];
                        sr[b] = rc.x;
                        nr[b] = __int_as_float(rc.y);
                    }
                }
#pragma unroll
                for (int b = 0; b < 4; ++b) {
                    if (b < nb) {
                        const float4* xr = x4 + (long)sr[b] * 32 + tq * 2;
                        ga[b][0] = xr[0];
                        ga[b][1] = xr[1];
                    }
                }
#pragma unroll
                for (int b = 0; b < 4; ++b) {
                    if (b < nb) {
                        uaA[0] += nr[b] * ga[b][0].x; uaA[1] += nr[b] * ga[b][0].y;
                        uaA[2] += nr[b] * ga[b][0].z; uaA[3] += nr[b] * ga[b][0].w;
                        uaA[4] += nr[b] * ga[b][1].x; uaA[5] += nr[b] * ga[b][1].y;
                        uaA[6] += nr[b] * ga[b][1].z; uaA[7] += nr[b] * ga[b][1].w;
                    }
                }
            }
        }
        // row B
        {
            const int q0 = (pB0 > cb) ? pB0 : cb;
            const int q1 = (pB1 < ce) ? pB1 : ce;
            for (int p = q0; p < q1; p += 4) {
                const int nb = q1 - p;
                int sr[4]; float nr[4];
                float4 ga[4][2];
#pragma unroll
                for (int b = 0; b < 4; ++b) {
                    if (b < nb) {
                        int2 rc = recs[p - cb + b];
                        sr[b] = rc.x;
                        nr[b] = __int_as_float(rc.y);
                    }
                }
#pragma unroll
                for (int b = 0; b < 4; ++b) {
                    if (b < nb) {
                        const float4* xr = x4 + (long)sr[b] * 32 + tq * 2;
                        ga[b][0] = xr[0];
                        ga[b][1] = xr[1];
                    }
                }
#pragma unroll
                for (int b = 0; b < 4; ++b) {
                    if (b < nb) {
                        uaB[0] += nr[b] * ga[b][0].x; uaB[1] += nr[b] * ga[b][0].y;
                        uaB[2] += nr[b] * ga[b][0].z; uaB[3] += nr[b] * ga[b][0].w;
                        uaB[4] += nr[b] * ga[b][1].x; uaB[5] += nr[b] * ga[b][1].y;
                        uaB[6] += nr[b] * ga[b][1].z; uaB[7] += nr[b] * ga[b][1].w;
                    }
                }
            }
        }
    }

    // ---- phase 3: write u-halves of A ----
    {
        ushort4 u0, u1;
        u0.x = f2bf(uaA[0]); u0.y = f2bf(uaA[1]); u0.z = f2bf(uaA[2]); u0.w = f2bf(uaA[3]);
        u1.x = f2bf(uaA[4]); u1.y = f2bf(uaA[5]); u1.z = f2bf(uaA[6]); u1.w = f2bf(uaA[7]);
        u16* up = &A[trow * 264 + tq * 8];
        *reinterpret_cast<ushort4*>(up) = u0;
        *reinterpret_cast<ushort4*>(up + 4) = u1;
        u0.x = f2bf(uaB[0]); u0.y = f2bf(uaB[1]); u0.z = f2bf(uaB[2]); u0.w = f2bf(uaB[3]);
        u1.x = f2bf(uaB[4]); u1.y = f2bf(uaB[5]); u1.z = f2bf(uaB[6]); u1.w = f2bf(uaB[7]);
        up = &A[(trow + 16) * 264 + tq * 8];
        *reinterpret_cast<ushort4*>(up) = u0;
        *reinterpret_cast<ushort4*>(up + 4) = u1;
    }
    __syncthreads();

    // ---- MFMA: each wave 32 rows x its 64 cols (B streamed from L2) ----
    f32x4 acc[2][4];
#pragma unroll
    for (int m = 0; m < 2; ++m)
#pragma unroll
        for (int t = 0; t < 4; ++t) acc[m][t] = (f32x4){0.f, 0.f, 0.f, 0.f};

    const int arowb = lane & 15;
    const int koff = (lane >> 4) * 8;
    const short8* wf = reinterpret_cast<const short8*>(wfrag);
#pragma unroll
    for (int s = 0; s < 8; ++s) {
#pragma unroll
        for (int m = 0; m < 2; ++m) {
            short8 af = *reinterpret_cast<const short8*>(
                &A[(m * 16 + arowb) * 264 + s * 32 + koff]);
#pragma unroll
            for (int t = 0; t < 4; ++t) {
                short8 bfr = wf[(s * 16 + (wv * 4 + t)) * 64 + lane];
                acc[m][t] = __builtin_amdgcn_mfma_f32_16x16x32_bf16(af, bfr, acc[m][t], 0, 0, 0);
            }
        }
    }

    // ---- epilogue: bias, per-row partial sums over this wave's 64 cols ----
    const int ncol = lane & 15;
    const int g = lane >> 4;
    float bcv[4];
#pragma unroll
    for (int t = 0; t < 4; ++t) bcv[t] = bc[wv * 64 + t * 16 + ncol];
#pragma unroll
    for (int m = 0; m < 2; ++m) {
#pragma unroll
        for (int j = 0; j < 4; ++j) {
            float s = 0.f, q = 0.f;
#pragma unroll
            for (int t = 0; t < 4; ++t) {
                float v = acc[m][t][j] + bcv[t];
                acc[m][t][j] = v;
                s += v;
                q += v * v;
            }
#pragma unroll
            for (int msk = 1; msk < 16; msk <<= 1) {
                s += __shfl_xor(s, msk);
                q += __shfl_xor(q, msk);
            }
            if (ncol == 0) {
                int row = m * 16 + g * 4 + j;
                red[(wv * 32 + row) * 2 + 0] = s;
                red[(wv * 32 + row) * 2 + 1] = q;
            }
        }
    }
    __syncthreads();
    if (tid < 64) {
        int row = tid >> 1, q = tid & 1;
        float t = 0.f;
#pragma unroll
        for (int w = 0; w < 4; ++w) t += red[(w * 32 + row) * 2 + q];
        fin[row * 2 + q] = t;
    }
    __syncthreads();

    // ---- LN + relu + store ----
    float gv[4], bv[4];
#pragma unroll
    for (int t = 0; t < 4; ++t) {
        gv[t] = gamma[wv * 64 + t * 16 + ncol];
        bv[t] = beta[wv * 64 + t * 16 + ncol];
    }
#pragma unroll
    for (int m = 0; m < 2; ++m) {
#pragma unroll
        for (int j = 0; j < 4; ++j) {
            int row = m * 16 + g * 4 + j;
            long rr = r0 + row;
            if (rr < N) {
                float mean = fin[row * 2] * (1.f / 256.f);
                float var = fin[row * 2 + 1] * (1.f / 256.f) - mean * mean;
                float rstd = rsqrtf(var + LN_EPS);
                float* op = out + rr * (long)OUT_C + wv * 64 + ncol;
#pragma unroll
                for (int t = 0; t < 4; ++t) {
                    float o = (acc[m][t][j] - mean) * rstd * gv[t] + bv[t];
                    op[t * 16] = fmaxf(o, 0.f);
                }
            }
        }
    }
}

extern "C" void kernel_launch(void* const* d_in, const int* in_sizes, int n_in,
                              void* d_out, int out_size, void* d_ws, size_t ws_size,
                              hipStream_t stream) {
    const float* x    = (const float*)d_in[0];
    const float* ew   = (const float*)d_in[1];
    const float* Wg   = (const float*)d_in[2];
    const float* bg   = (const float*)d_in[3];
    const float* Wr   = (const float*)d_in[4];
    const float* br   = (const float*)d_in[5];
    const float* gm   = (const float*)d_in[6];
    const float* bt   = (const float*)d_in[7];
    const int*   ei   = (const int*)d_in[8];

    const int N = in_sizes[0] / IN_C;
    const int E = in_sizes[8] / 2;
    const int NB1 = (N + 1023) / 1024;   // <= 512
    const int NBC = (E + 255) / 256;

    // ws layout: rec2 | pk (u64 packed cnt/deg) | dinv | off | cur | part | wfrag | bc
    int2*  rec2 = (int2*)d_ws;                        // E int2
    u64*   pk   = (u64*)(rec2 + E);                   // N u64 (8B aligned)
    float* dinv = (float*)(pk + N);                   // N f32
    int*   off  = (int*)(dinv + N);                   // N+1 i32
    int*   cur  = off + N + 1;                        // N i32
    int*   part = cur + N;                            // 512 i32
    u16*   wfrag = (u16*)(part + 512);                // 65536 bf16
    float* bc   = (float*)(wfrag + 65536);            // 256 f32

    const int n4 = (2 * N + 3) / 4;      // pk bytes as float4 count
    k_zero<<<(n4 + 255) / 256, 256, 0, stream>>>((float4*)pk, n4);
    k_count<<<NBC + 32, 256, 0, stream>>>(ei, ew, pk, E, NBC,
                                          Wg, Wr, bg, br, wfrag, bc);
    k_scan1<<<NB1, 256, 0, stream>>>(pk, part, dinv, N);
    k_scan2<<<1, 512, 0, stream>>>(part, NB1);
    k_scan3<<<NB1, 256, 0, stream>>>(pk, part, off, cur, N, E);
    k_place<<<(E + 255) / 256, 256, 0, stream>>>(ei, ew, dinv, cur, rec2, E);
    k_gemm<<<(N + 31) / 32, 256, 0, stream>>>((const float4*)x, dinv, off, rec2,
                                              wfrag, bc, gm, bt, (float*)d_out, N);
}

// Round 16
// 410.534 us; speedup vs baseline: 1.0343x; 1.0343x over previous
//
#include <hip/hip_runtime.h>
#include <hip/hip_bf16.h>

typedef __attribute__((ext_vector_type(8))) short short8;
typedef __attribute__((ext_vector_type(8))) unsigned short ushort8;
typedef __attribute__((ext_vector_type(4))) float f32x4;
typedef unsigned short u16;
typedef unsigned long long u64;

#define IN_C 128
#define OUT_C 256
#define LN_EPS 1e-5f
#define CHUNK 512
#define WSCALE 1048576.0f   // 2^20 fixed-point for packed degree

__device__ __forceinline__ u16 f2bf(float f) {
    __hip_bfloat16 h = __float2bfloat16(f);
    return __builtin_bit_cast(u16, h);
}

// zero pk[N] (8N bytes) with vector stores
__global__ void k_zero(float4* __restrict__ p, int n4) {
    int i = blockIdx.x * 256 + threadIdx.x;
    if (i < n4) p[i] = make_float4(0.f, 0.f, 0.f, 0.f);
}

// Fused: packed {count, weighted-degree} histogram (blocks [0,nbc)) and
// W-fragment pack + combined bias (blocks [nbc, nbc+32)).
__global__ void k_count(const int* __restrict__ ei, const float* __restrict__ ew,
                        u64* __restrict__ pk, int E, int nbc,
                        const float* __restrict__ Wg, const float* __restrict__ Wr,
                        const float* __restrict__ bg, const float* __restrict__ br,
                        u16* __restrict__ wfrag, float* __restrict__ bc) {
    int b = blockIdx.x;
    if (b < nbc) {
        int e = b * 256 + threadIdx.x;
        if (e < E) {
            int c = ei[E + e];
            unsigned w = (unsigned)(ew[e & 31] * WSCALE + 0.5f);
            atomicAdd(&pk[c], (1ULL << 32) | (u64)w);
        }
        return;
    }
    // ---- wprep part ----
    int tid = (b - nbc) * 256 + threadIdx.x;
    if (tid < OUT_C) bc[tid] = bg[tid] + br[tid];
    if (tid >= 8192) return;
    int l = tid & 63;
    int t = (tid >> 6) & 15;
    int s = tid >> 10;
    int n = t * 16 + (l & 15);
    int k0 = s * 32 + (l >> 4) * 8;
    short8 pkk;
#pragma unroll
    for (int j = 0; j < 8; ++j) {
        int k = k0 + j;
        float w = (k < IN_C) ? Wg[k * OUT_C + n] : Wr[(k - IN_C) * OUT_C + n];
        pkk[j] = (short)f2bf(w);
    }
    reinterpret_cast<short8*>(wfrag)[tid] = pkk;
}

// ---- exclusive scan of cnt -> off, cur = copy; dinv computed from packed ----
__global__ void k_scan1(const u64* __restrict__ pk, int* __restrict__ partial,
                        float* __restrict__ dinv, int n) {
    __shared__ int sm[256];
    int b = blockIdx.x, t = threadIdx.x;
    int base = b * 1024 + t * 4;
    int s = 0;
#pragma unroll
    for (int k = 0; k < 4; ++k) {
        int i = base + k;
        if (i < n) {
            u64 v = pk[i];
            s += (int)(v >> 32);
            dinv[i] = rsqrtf(1.0f + (float)(unsigned)(v & 0xffffffffULL) * (1.0f / WSCALE));
        }
    }
    sm[t] = s; __syncthreads();
    for (int m = 128; m > 0; m >>= 1) { if (t < m) sm[t] += sm[t + m]; __syncthreads(); }
    if (t == 0) partial[b] = sm[0];
}

__global__ void k_scan2(int* __restrict__ partial, int nb) {
    __shared__ int sm[512];
    int t = threadIdx.x;
    sm[t] = (t < nb) ? partial[t] : 0;
    __syncthreads();
    for (int d = 1; d < 512; d <<= 1) {
        int v = (t >= d) ? sm[t - d] : 0;
        __syncthreads();
        sm[t] += v;
        __syncthreads();
    }
    if (t < nb) partial[t] = (t == 0) ? 0 : sm[t - 1];
}

__global__ void k_scan3(const u64* __restrict__ pk, const int* __restrict__ partial,
                        int* __restrict__ off, int* __restrict__ cur, int n, int E) {
    __shared__ int sm[256];
    int b = blockIdx.x, t = threadIdx.x;
    int base = b * 1024 + t * 4;
    int c[4]; int s = 0;
#pragma unroll
    for (int k = 0; k < 4; ++k) {
        int i = base + k;
        c[k] = (i < n) ? (int)(pk[i] >> 32) : 0;
        s += c[k];
    }
    sm[t] = s; __syncthreads();
    for (int d = 1; d < 256; d <<= 1) {
        int v = (t >= d) ? sm[t - d] : 0;
        __syncthreads();
        sm[t] += v;
        __syncthreads();
    }
    int run = partial[b] + (sm[t] - s);
#pragma unroll
    for (int k = 0; k < 4; ++k) {
        int i = base + k;
        if (i < n) { off[i] = run; cur[i] = run; }
        run += c[k];
    }
    if (b == 0 && t == 0) off[n] = E;
}

// place edge records {src, norm} grouped by target col
__global__ void k_place(const int* __restrict__ ei, const float* __restrict__ ew,
                        const float* __restrict__ dinv, int* __restrict__ cur,
                        int2* __restrict__ rec2, int E) {
    int e = blockIdx.x * 256 + threadIdx.x;
    if (e >= E) return;
    int r = ei[e], c = ei[E + e];
    float nrm = dinv[r] * ew[e & 31] * dinv[c];
    int p = atomicAdd(&cur[c], 1);
    rec2[p] = make_int2(r, __float_as_int(nrm));
}

// Fused: LDS-staged CSR records + batched independent gathers (register accum)
// -> bf16 LDS-A ; h = [u|x]@Wc+bc ; LN ; relu ; store.
// BM=32 rows/block, 512 threads = 8 waves; wave wv owns cols [wv*32, wv*32+32).
__global__ __launch_bounds__(512, 4) void k_gemm(
    const float4* __restrict__ x4, const float* __restrict__ dinv,
    const int* __restrict__ off, const int2* __restrict__ rec2g,
    const u16* __restrict__ wfrag, const float* __restrict__ bc,
    const float* __restrict__ gamma, const float* __restrict__ beta,
    float* __restrict__ out, int N) {

    __shared__ u16 A[32 * 264];      // [32 rows][256 bf16 + 8 pad]: 0..127 u, 128..255 x
    __shared__ float red[8 * 32 * 2];
    __shared__ float fin[32 * 2];
    __shared__ int2 recs[CHUNK];     // staged CSR records for this block

    const int tid = threadIdx.x;
    const int lane = tid & 63;
    const int wv = tid >> 6;
    const long r0 = (long)blockIdx.x * 32;

    const int trow = tid >> 4;       // 0..31
    const int tq = tid & 15;         // owns floats [tq*8, tq*8+8)
    const long gr = r0 + trow;

    // ---- phase 1: self-loop init in regs + x-half of A ----
    float ua[8];
    int p0 = 0, p1 = 0;
    {
        u16* xp = &A[trow * 264 + 128 + tq * 8];
        if (gr < N) {
            float d = dinv[gr];
            float d2 = d * d;
            const float4* xs = x4 + gr * 32 + tq * 2;
            float4 v0 = xs[0], v1 = xs[1];
            ushort4 x0, x1;
            x0.x = f2bf(v0.x); x0.y = f2bf(v0.y); x0.z = f2bf(v0.z); x0.w = f2bf(v0.w);
            x1.x = f2bf(v1.x); x1.y = f2bf(v1.y); x1.z = f2bf(v1.z); x1.w = f2bf(v1.w);
            *reinterpret_cast<ushort4*>(xp) = x0;
            *reinterpret_cast<ushort4*>(xp + 4) = x1;
            ua[0] = v0.x * d2; ua[1] = v0.y * d2; ua[2] = v0.z * d2; ua[3] = v0.w * d2;
            ua[4] = v1.x * d2; ua[5] = v1.y * d2; ua[6] = v1.z * d2; ua[7] = v1.w * d2;
            p0 = off[gr]; p1 = off[gr + 1];
        } else {
#pragma unroll
            for (int k = 0; k < 8; ++k) ua[k] = 0.f;
            ushort4 zz = {0, 0, 0, 0};
            *reinterpret_cast<ushort4*>(xp) = zz;
            *reinterpret_cast<ushort4*>(xp + 4) = zz;
        }
    }

    // ---- phase 2: chunked record staging + batched independent gathers ----
    const int rend = (int)((r0 + 32 < N) ? (r0 + 32) : N);
    const int e0 = off[r0];
    const int e1 = off[rend];
    for (int cb = e0; cb < e1; cb += CHUNK) {
        const int ce = (cb + CHUNK < e1) ? (cb + CHUNK) : e1;
        __syncthreads();   // recs reuse guard (no-op cost on first iter)
        for (int i = tid; i < ce - cb; i += 512) recs[i] = rec2g[cb + i];
        __syncthreads();
        const int q0 = (p0 > cb) ? p0 : cb;
        const int q1 = (p1 < ce) ? p1 : ce;
        for (int p = q0; p < q1; p += 4) {
            const int nb = q1 - p;   // clamp to 4 via b<nb guards
            int sr[4]; float nr[4];
            float4 ga[4][2];
#pragma unroll
            for (int b = 0; b < 4; ++b) {
                if (b < nb) {
                    int2 rc = recs[p - cb + b];
                    sr[b] = rc.x;
                    nr[b] = __int_as_float(rc.y);
                }
            }
#pragma unroll
            for (int b = 0; b < 4; ++b) {
                if (b < nb) {
                    const float4* xr = x4 + (long)sr[b] * 32 + tq * 2;
                    ga[b][0] = xr[0];
                    ga[b][1] = xr[1];
                }
            }
#pragma unroll
            for (int b = 0; b < 4; ++b) {
                if (b < nb) {
                    ua[0] += nr[b] * ga[b][0].x; ua[1] += nr[b] * ga[b][0].y;
                    ua[2] += nr[b] * ga[b][0].z; ua[3] += nr[b] * ga[b][0].w;
                    ua[4] += nr[b] * ga[b][1].x; ua[5] += nr[b] * ga[b][1].y;
                    ua[6] += nr[b] * ga[b][1].z; ua[7] += nr[b] * ga[b][1].w;
                }
            }
        }
    }

    // ---- phase 3: write u-half of A ----
    {
        ushort4 u0, u1;
        u0.x = f2bf(ua[0]); u0.y = f2bf(ua[1]); u0.z = f2bf(ua[2]); u0.w = f2bf(ua[3]);
        u1.x = f2bf(ua[4]); u1.y = f2bf(ua[5]); u1.z = f2bf(ua[6]); u1.w = f2bf(ua[7]);
        u16* up = &A[trow * 264 + tq * 8];
        *reinterpret_cast<ushort4*>(up) = u0;
        *reinterpret_cast<ushort4*>(up + 4) = u1;
    }
    __syncthreads();

    // ---- B-slice load (after staging to keep staging-phase VGPR low) ----
    const short8* wf = reinterpret_cast<const short8*>(wfrag);
    short8 bfr[8][2];
#pragma unroll
    for (int s = 0; s < 8; ++s) {
#pragma unroll
        for (int t = 0; t < 2; ++t)
            bfr[s][t] = wf[(s * 16 + (wv * 2 + t)) * 64 + lane];
    }

    // ---- MFMA: each wave 32 rows x its 32 cols, B in registers ----
    f32x4 acc[2][2];
#pragma unroll
    for (int m = 0; m < 2; ++m)
#pragma unroll
        for (int t = 0; t < 2; ++t) acc[m][t] = (f32x4){0.f, 0.f, 0.f, 0.f};

    const int arowb = lane & 15;
    const int koff = (lane >> 4) * 8;
#pragma unroll
    for (int s = 0; s < 8; ++s) {
#pragma unroll
        for (int m = 0; m < 2; ++m) {
            short8 af = *reinterpret_cast<const short8*>(
                &A[(m * 16 + arowb) * 264 + s * 32 + koff]);
#pragma unroll
            for (int t = 0; t < 2; ++t)
                acc[m][t] = __builtin_amdgcn_mfma_f32_16x16x32_bf16(af, bfr[s][t], acc[m][t], 0, 0, 0);
        }
    }

    // ---- epilogue: bias, per-row partial sums over this wave's 32 cols ----
    const int ncol = lane & 15;
    const int g = lane >> 4;
    const float bc0 = bc[wv * 32 + ncol];
    const float bc1 = bc[wv * 32 + 16 + ncol];
#pragma unroll
    for (int m = 0; m < 2; ++m) {
#pragma unroll
        for (int j = 0; j < 4; ++j) {
            float v0 = acc[m][0][j] + bc0;
            float v1 = acc[m][1][j] + bc1;
            acc[m][0][j] = v0;
            acc[m][1][j] = v1;
            float s = v0 + v1;
            float q = v0 * v0 + v1 * v1;
#pragma unroll
            for (int msk = 1; msk < 16; msk <<= 1) {
                s += __shfl_xor(s, msk);
                q += __shfl_xor(q, msk);
            }
            if (ncol == 0) {
                int row = m * 16 + g * 4 + j;
                red[(wv * 32 + row) * 2 + 0] = s;
                red[(wv * 32 + row) * 2 + 1] = q;
            }
        }
    }
    __syncthreads();
    if (tid < 64) {
        int row = tid >> 1, q = tid & 1;
        float t = 0.f;
#pragma unroll
        for (int w = 0; w < 8; ++w) t += red[(w * 32 + row) * 2 + q];
        fin[row * 2 + q] = t;
    }
    __syncthreads();

    // ---- LN + relu + store ----
    const float gv0 = gamma[wv * 32 + ncol], bv0 = beta[wv * 32 + ncol];
    const float gv1 = gamma[wv * 32 + 16 + ncol], bv1 = beta[wv * 32 + 16 + ncol];
#pragma unroll
    for (int m = 0; m < 2; ++m) {
#pragma unroll
        for (int j = 0; j < 4; ++j) {
            int row = m * 16 + g * 4 + j;
            long rr = r0 + row;
            if (rr < N) {
                float mean = fin[row * 2] * (1.f / 256.f);
                float var = fin[row * 2 + 1] * (1.f / 256.f) - mean * mean;
                float rstd = rsqrtf(var + LN_EPS);
                float o0 = (acc[m][0][j] - mean) * rstd * gv0 + bv0;
                float o1 = (acc[m][1][j] - mean) * rstd * gv1 + bv1;
                float* op = out + rr * (long)OUT_C + wv * 32 + ncol;
                op[0]  = fmaxf(o0, 0.f);
                op[16] = fmaxf(o1, 0.f);
            }
        }
    }
}

extern "C" void kernel_launch(void* const* d_in, const int* in_sizes, int n_in,
                              void* d_out, int out_size, void* d_ws, size_t ws_size,
                              hipStream_t stream) {
    const float* x    = (const float*)d_in[0];
    const float* ew   = (const float*)d_in[1];
    const float* Wg   = (const float*)d_in[2];
    const float* bg   = (const float*)d_in[3];
    const float* Wr   = (const float*)d_in[4];
    const float* br   = (const float*)d_in[5];
    const float* gm   = (const float*)d_in[6];
    const float* bt   = (const float*)d_in[7];
    const int*   ei   = (const int*)d_in[8];

    const int N = in_sizes[0] / IN_C;
    const int E = in_sizes[8] / 2;
    const int NB1 = (N + 1023) / 1024;   // <= 512
    const int NBC = (E + 255) / 256;

    // ws layout: rec2 | pk (u64 packed cnt/deg) | dinv | off | cur | part | wfrag | bc
    int2*  rec2 = (int2*)d_ws;                        // E int2
    u64*   pk   = (u64*)(rec2 + E);                   // N u64 (8B aligned)
    float* dinv = (float*)(pk + N);                   // N f32
    int*   off  = (int*)(dinv + N);                   // N+1 i32
    int*   cur  = off + N + 1;                        // N i32
    int*   part = cur + N;                            // 512 i32
    u16*   wfrag = (u16*)(part + 512);                // 65536 bf16
    float* bc   = (float*)(wfrag + 65536);            // 256 f32

    const int n4 = (2 * N + 3) / 4;      // pk bytes as float4 count
    k_zero<<<(n4 + 255) / 256, 256, 0, stream>>>((float4*)pk, n4);
    k_count<<<NBC + 32, 256, 0, stream>>>(ei, ew, pk, E, NBC,
                                          Wg, Wr, bg, br, wfrag, bc);
    k_scan1<<<NB1, 256, 0, stream>>>(pk, part, dinv, N);
    k_scan2<<<1, 512, 0, stream>>>(part, NB1);
    k_scan3<<<NB1, 256, 0, stream>>>(pk, part, off, cur, N, E);
    k_place<<<(E + 255) / 256, 256, 0, stream>>>(ei, ew, dinv, cur, rec2, E);
    k_gemm<<<(N + 31) / 32, 512, 0, stream>>>((const float4*)x, dinv, off, rec2,
                                              wfrag, bc, gm, bt, (float*)d_out, N);
}